// Round 17
// baseline (97.868 us; speedup 1.0000x reference)
//
#include <hip/hip_runtime.h>

typedef float  f32x4 __attribute__((ext_vector_type(4)));
typedef short  s16x8 __attribute__((ext_vector_type(8)));
typedef unsigned short u16;
typedef u16    u16x4 __attribute__((ext_vector_type(4)));

#define TIMESTEPS 1000

// ---- ws float-offset map ----
#define WS_ALPHAS   0        // 1000 f
#define WS_FREQS    1024     // 256 f
#define WS_PROBS    1536     // 512*6 f
#define WS_SELECTED 4608     // 512 int
#define WS_LOSSB    5632     // 1024 f (raw sums; [half*512+b], written once each)
#define WS_PARTS    7680     // 52 f
#define WS_FLAG     7744     // 1 int (k5 join; reset by k3 block 0)
#define WS_HSTATB   8192     // 512*512 f (K-half-1 of hstat)
#define WS_XC       270336   // 512*1024 bf16 (u16)
#define WS_HSTAT    532480   // 512*512 f (K-half-0 of hstat)
#define WS_HSTAT2   794624   // 6*4*512 f (aux half-0)
#define WS_OUTSUB   806912   // 6*4*64*64 f
#define WS_BIAS     2691072  // 512*512 f (k1 input; k3 reuses head as HSTAT2B)
#define WS_HSTAT2B  2691072  // 6*4*512 f (aux half-1; reuses BIAS after k1)
#define WS_U16BYTE  3620864  // byte offset of u16 weight region
// u16-offsets inside u16 region
#define U_WENCT     0        // 512*64
#define U_W1T       32768    // 6*512*1088
#define U_W2T       3375104  // 6*64*512

__device__ __forceinline__ u16 f2bf(float x){
    unsigned u = __builtin_bit_cast(unsigned, x);
    unsigned r = (u + 0x7FFFu + ((u >> 16) & 1u)) >> 16;
    return (u16)r;
}

// exp2-based tanh-gelu: gelu = x - x/(exp2(x*(a*x^2+b)) + 1), a,b pre-scaled by 2/ln2.
__device__ __forceinline__ float gelu_f(float x){
    float arg = x * fmaf(0.102939240f, x*x, 2.302032318f);
    float ex  = __builtin_amdgcn_exp2f(arg);
    float r   = __builtin_amdgcn_rcpf(ex + 1.0f);
    return fmaf(-x, r, x);
}

__device__ __forceinline__ void mfma16(f32x4& c, s16x8 a, s16x8 b){
    asm volatile("v_mfma_f32_16x16x32_bf16 %0, %1, %2, %0" : "+v"(c) : "v"(a), "v"(b));
}

// ---------------- k0: init + bias table + ALL transposes (64x64 tiles) ----------------
__global__ __launch_bounds__(256) void k0(const float* __restrict__ Wenc,
        const float* __restrict__ W1, const float* __restrict__ W2,
        const float* __restrict__ stat, const float* __restrict__ Wstat,
        const float* __restrict__ benc, u16* __restrict__ uws, float* __restrict__ ws){
    __shared__ float sT[64][65];
    float* sp = &sT[0][0];
    int bid = blockIdx.x, tid = threadIdx.x;
    if(bid == 0){
        ws[WS_FREQS + tid] = expf(-logf(10000.0f) * (float)tid / 256.0f);
        float p = 1.f;
        #pragma unroll
        for(int r = 0; r < 4; r++){
            int i = tid*4 + r;
            if(i < TIMESTEPS){
                float beta = 0.0001f + (0.02f - 0.0001f) * ((float)i / 999.0f);
                p *= (1.0f - beta);
            }
        }
        sp[tid] = p;
        __syncthreads();
        for(int st = 1; st < 256; st <<= 1){
            float v = (tid >= st) ? sp[tid - st] : 1.0f;
            __syncthreads();
            sp[tid] *= v;
            __syncthreads();
        }
        float run = (tid == 0) ? 1.0f : sp[tid - 1];
        for(int r = 0; r < 4; r++){
            int i = tid*4 + r;
            if(i < TIMESTEPS){
                float beta = 0.0001f + (0.02f - 0.0001f) * ((float)i / 999.0f);
                run *= (1.0f - beta);
                ws[WS_ALPHAS + i] = run;
            }
        }
        return;
    }
    if(bid <= 8){
        int jt = bid - 1;
        int r = tid >> 2, c0 = (tid & 3) * 16;
        #pragma unroll
        for(int i = 0; i < 4; i++)
            *(f32x4*)&sT[r][c0 + i*4] = *(const f32x4*)&Wenc[(size_t)r*512 + jt*64 + c0 + i*4];
        __syncthreads();
        u16* dst = uws + U_WENCT + (size_t)(jt*64 + r)*64;
        #pragma unroll
        for(int i = 0; i < 4; i++){
            u16x4 pk;
            pk.x = f2bf(sT[c0 + i*4 + 0][r]); pk.y = f2bf(sT[c0 + i*4 + 1][r]);
            pk.z = f2bf(sT[c0 + i*4 + 2][r]); pk.w = f2bf(sT[c0 + i*4 + 3][r]);
            *(u16x4*)&dst[c0 + i*4] = pk;
        }
        return;
    }
    if(bid <= 72){
        float* sSt = sp;
        int g = bid - 9, b0 = g*8;
        sSt[tid] = stat[b0*32 + tid];
        __syncthreads();
        #pragma unroll
        for(int half = 0; half < 2; half++){
            int j = tid + half*256;
            float acc[8] = {0,0,0,0,0,0,0,0};
            for(int s = 0; s < 32; s++){
                float wv = Wstat[s*512 + j];
                #pragma unroll
                for(int bb = 0; bb < 8; bb++) acc[bb] += sSt[bb*32 + s] * wv;
            }
            float bz = benc[j];
            #pragma unroll
            for(int bb = 0; bb < 8; bb++)
                ws[WS_BIAS + (b0 + bb)*512 + j] = acc[bb] + bz;
        }
        return;
    }
    int t = bid - 73;
    const float* src; u16* dst; int K, J, kt, jt;
    if(t < 816){
        int e = t / 136, r = t % 136; kt = r >> 3; jt = r & 7;
        src = W1 + (size_t)e*1088*512; dst = uws + U_W1T + (size_t)e*512*1088; K = 1088; J = 512;
    } else {
        int t2 = t - 816; int e = t2 >> 3; kt = t2 & 7; jt = 0;
        src = W2 + (size_t)e*512*64; dst = uws + U_W2T + (size_t)e*64*512; K = 512; J = 64;
    }
    int r = tid >> 2, c0 = (tid & 3) * 16;
    #pragma unroll
    for(int i = 0; i < 4; i++)
        *(f32x4*)&sT[r][c0 + i*4] = *(const f32x4*)&src[(size_t)(kt*64 + r)*J + jt*64 + c0 + i*4];
    __syncthreads();
    u16* d2 = dst + (size_t)(jt*64 + r)*K + kt*64;
    #pragma unroll
    for(int i = 0; i < 4; i++){
        u16x4 pk;
        pk.x = f2bf(sT[c0 + i*4 + 0][r]); pk.y = f2bf(sT[c0 + i*4 + 1][r]);
        pk.z = f2bf(sT[c0 + i*4 + 2][r]); pk.w = f2bf(sT[c0 + i*4 + 3][r]);
        *(u16x4*)&d2[c0 + i*4] = pk;
    }
}

// ---------------- k1: encoder + router, 1024 threads, 2-deep LDS pipeline --------
#define PADX 72
__global__ __launch_bounds__(1024) void k1_enc(const float* __restrict__ obs,
        const u16* __restrict__ uws, const float* __restrict__ Wr,
        const float* __restrict__ br, const int* __restrict__ phase,
        const int* __restrict__ t_arr, float* __restrict__ ws){
    __shared__ u16  sX[256 * PADX];
    __shared__ float sBias[512];
    __shared__ float sG[512];
    __shared__ float sRed[8][6];
    int b = blockIdx.x, tid = threadIdx.x;
    {
        int row = tid >> 2, c0 = (tid & 3) * 16;
        const f32x4* src = (const f32x4*)&obs[((size_t)b*256 + row)*64 + c0];
        u16* dst = &sX[row*PADX + c0];
        #pragma unroll
        for(int i = 0; i < 4; i++){
            f32x4 v = src[i];
            u16x4 pk; pk.x = f2bf(v.x); pk.y = f2bf(v.y); pk.z = f2bf(v.z); pk.w = f2bf(v.w);
            *(u16x4*)(dst + i*4) = pk;
        }
    }
    if(tid < 512) sBias[tid] = ws[WS_BIAS + b*512 + tid];
    __syncthreads();
    int w = tid >> 6, l = tid & 63, lr = l & 15, lk = (l >> 4) * 8;
    const u16* wencT = uws + U_WENCT;
    s16x8 bf[2][2];
    float bias[2];
    #pragma unroll
    for(int n = 0; n < 2; n++){
        int col = w*32 + n*16 + lr;
        bf[n][0] = *(const s16x8*)&wencT[col*64 + lk];
        bf[n][1] = *(const s16x8*)&wencT[col*64 + 32 + lk];
        bias[n]  = sBias[col];
    }
    float cac[2] = {0.f, 0.f};
    // 2-deep software pipeline: prefetch next mt's A-fragments during gelu
    s16x8 a0 = *(const s16x8*)&sX[lr*PADX + lk];
    s16x8 a1 = *(const s16x8*)&sX[lr*PADX + 32 + lk];
    for(int mt = 0; mt < 16; mt++){
        int nrow = (((mt + 1) & 15)*16 + lr)*PADX;
        s16x8 na0 = *(const s16x8*)&sX[nrow + lk];
        s16x8 na1 = *(const s16x8*)&sX[nrow + 32 + lk];
        #pragma unroll
        for(int n = 0; n < 2; n++){
            f32x4 acc = {bias[n], bias[n], bias[n], bias[n]};
            mfma16(acc, a0, bf[n][0]);
            mfma16(acc, a1, bf[n][1]);
            cac[n] += gelu_f(acc.x) + gelu_f(acc.y) + gelu_f(acc.z) + gelu_f(acc.w);
        }
        a0 = na0; a1 = na1;
    }
    #pragma unroll
    for(int n = 0; n < 2; n++){
        cac[n] += __shfl_xor(cac[n], 16);
        cac[n] += __shfl_xor(cac[n], 32);
    }
    if(l < 16){
        #pragma unroll
        for(int n = 0; n < 2; n++)
            sG[w*32 + n*16 + l] = cac[n] * (1.0f/256.0f);
    }
    __syncthreads();
    if(tid < 512){
        float gv = sG[tid];
        u16* XC = (u16*)(ws + WS_XC);
        XC[b*1024 + tid] = f2bf(gv);
        int tv = t_arr[b];
        float fr = ws[WS_FREQS + (tid & 255)];
        float ang = (float)tv * fr;
        XC[b*1024 + 512 + tid] = f2bf((tid < 256) ? sinf(ang) : cosf(ang));
        float p6[6];
        #pragma unroll
        for(int e = 0; e < 6; e++) p6[e] = gv * Wr[tid*6 + e];
        #pragma unroll
        for(int off = 32; off > 0; off >>= 1)
            #pragma unroll
            for(int e = 0; e < 6; e++) p6[e] += __shfl_down(p6[e], off);
        if(l == 0)
            #pragma unroll
            for(int e = 0; e < 6; e++) sRed[w][e] = p6[e];
    }
    __syncthreads();
    if(tid == 0){
        float logit[6], mx = -1e30f;
        #pragma unroll
        for(int e = 0; e < 6; e++){
            float s = 0.f;
            #pragma unroll
            for(int q = 0; q < 8; q++) s += sRed[q][e];
            logit[e] = s + br[e];
            mx = fmaxf(mx, logit[e]);
        }
        float s = 0.f, p[6];
        #pragma unroll
        for(int e = 0; e < 6; e++){
            p[e] = __builtin_amdgcn_exp2f((logit[e] - mx) * 1.44269504f);
            s += p[e];
        }
        float inv = 1.0f / s;
        #pragma unroll
        for(int e = 0; e < 6; e++) ws[WS_PROBS + b*6 + e] = p[e] * inv;
        int ph = phase[b];
        int sel = ph + ((logit[ph + 3] > logit[ph]) ? 3 : 0);
        ((int*)ws)[WS_SELECTED + b] = sel;
    }
}

// ---------------- k3: hstat GEMM, K-split x2 (grid 224 = 14 chunks x 8 jt x 2 kh) --------
__global__ __launch_bounds__(256) void k3_hstat(const u16* __restrict__ uws,
        const float* __restrict__ b1, float* __restrict__ ws){
    __shared__ int sSrc[64], sDst[64];
    __shared__ int sCnt[8][6], sBase[8][6], sSec[6], sTot[6];
    __shared__ int sChunk[16][3];
    __shared__ int sNch;
    int bid = blockIdx.x, tid = threadIdx.x;
    int w = tid >> 6, l = tid & 63;
    int* wsi = (int*)ws;
    if(bid == 0 && tid == 0) wsi[WS_FLAG] = 0;   // reset k5 join counter
    int kh = bid & 1, jt = (bid >> 1) & 7, c = bid >> 4;
    int sv0 = wsi[WS_SELECTED + tid];
    int sv1 = wsi[WS_SELECTED + 256 + tid];
    unsigned long long mym0 = 0, mym1 = 0;
    #pragma unroll
    for(int e = 0; e < 6; e++){
        unsigned long long m0 = __ballot(sv0 == e);
        unsigned long long m1 = __ballot(sv1 == e);
        if(l == 0){ sCnt[w][e] = __popcll(m0); sCnt[4 + w][e] = __popcll(m1); }
        if(sv0 == e) mym0 = m0;
        if(sv1 == e) mym1 = m1;
    }
    if(tid < 64){ sSrc[tid] = 0; sDst[tid] = -1; }
    __syncthreads();
    if(tid == 0){
        int o = 0;
        for(int e = 0; e < 6; e++){
            sSec[e] = o; int t0 = 0;
            for(int g = 0; g < 8; g++){ sBase[g][e] = o; o += sCnt[g][e]; t0 += sCnt[g][e]; }
            sTot[e] = t0; o += 4;
        }
        int nch = 0;
        for(int e = 0; e < 6; e++){
            int len = sTot[e] + 4, st = sSec[e];
            for(int s = 0; s < len; s += 64){
                sChunk[nch][0] = e; sChunk[nch][1] = st + s;
                sChunk[nch][2] = (len - s < 64) ? (len - s) : 64; nch++;
            }
        }
        sNch = nch;
    }
    __syncthreads();
    if(c >= sNch) return;
    int e     = sChunk[c][0];
    int start = sChunk[c][1];
    int len   = sChunk[c][2];
    int hstatD  = kh ? WS_HSTATB  : WS_HSTAT;
    int hstat2D = kh ? WS_HSTAT2B : WS_HSTAT2;
    {
        int rank = __popcll(mym0 & ((1ull << l) - 1ull));
        int pos = sBase[w][sv0] + rank - start;
        if(pos >= 0 && pos < len){ sSrc[pos] = tid; sDst[pos] = hstatD + tid*512; }
    }
    {
        int rank = __popcll(mym1 & ((1ull << l) - 1ull));
        int pos = sBase[4 + w][sv1] + rank - start;
        if(pos >= 0 && pos < len){ sSrc[pos] = 256 + tid; sDst[pos] = hstatD + (256 + tid)*512; }
    }
    if(tid < 24){
        int ea = tid >> 2, ba = tid & 3;
        int pos = sSec[ea] + sTot[ea] + ba - start;
        if(pos >= 0 && pos < len){ sSrc[pos] = ba; sDst[pos] = hstat2D + (ea*4 + ba)*512; }
    }
    __syncthreads();
    int lr = l & 15, lk = (l >> 4) * 8;
    int col = jt*64 + w*16 + lr;
    const u16* XC = (const u16*)(ws + WS_XC);
    const u16* rowA[4];
    #pragma unroll
    for(int mt = 0; mt < 4; mt++)
        rowA[mt] = XC + (size_t)sSrc[mt*16 + lr]*1024 + kh*512 + lk;
    const u16* bp = uws + U_W1T + ((size_t)e*512 + col)*1088 + 64 + kh*512 + lk;
    f32x4 acc[4];
    {
        float bv = kh ? 0.f : b1[e*512 + col];
        f32x4 z = {bv, bv, bv, bv};
        #pragma unroll
        for(int mt = 0; mt < 4; mt++) acc[mt] = z;
    }
    #pragma unroll 4
    for(int ks = 0; ks < 16; ks++){
        s16x8 bb = *(const s16x8*)(bp + ks*32);
        s16x8 a0 = *(const s16x8*)(rowA[0] + ks*32);
        s16x8 a1 = *(const s16x8*)(rowA[1] + ks*32);
        s16x8 a2 = *(const s16x8*)(rowA[2] + ks*32);
        s16x8 a3 = *(const s16x8*)(rowA[3] + ks*32);
        mfma16(acc[0], a0, bb);
        mfma16(acc[1], a1, bb);
        mfma16(acc[2], a2, bb);
        mfma16(acc[3], a3, bb);
    }
    #pragma unroll
    for(int mt = 0; mt < 4; mt++){
        #pragma unroll
        for(int rg = 0; rg < 4; rg++){
            int r = mt*16 + (l >> 4)*4 + rg;
            int d = sDst[r];
            if(d >= 0) ws[d + col] = acc[mt][rg];
        }
    }
}

// ---------------- k4: FFN, 256 thr, 32-tf halves (grid 1072), pipelined h-head ------------
#define PADN 72
#define PADH 520
__global__ __launch_bounds__(256) void k4_ffn(const float* __restrict__ fut,
        const float* __restrict__ eps, const int* __restrict__ t_arr,
        const u16* __restrict__ uws, const float* __restrict__ b2,
        float* __restrict__ ws){
    __shared__ u16 sN[32 * PADN];
    __shared__ u16 sH[32 * PADH];    // [tf][j]
    __shared__ float sHs[512];
    __shared__ float sRed[4];
    int tid = threadIdx.x, bid = blockIdx.x;
    int* wsi = (int*)ws;
    int b, e, store, half;
    if(bid < 48){ int idx = bid >> 1; half = bid & 1; e = idx >> 2; b = idx & 3; store = 1; }
    else { int r = bid - 48; b = r >> 1; half = r & 1; e = wsi[WS_SELECTED + b]; store = 0; }
    int tf0 = half * 32;
    if(store){
        int i2 = (e*4 + b)*512;
        sHs[tid]       = ws[WS_HSTAT2 + i2 + tid]       + ws[WS_HSTAT2B + i2 + tid];
        sHs[tid + 256] = ws[WS_HSTAT2 + i2 + tid + 256] + ws[WS_HSTAT2B + i2 + tid + 256];
    } else {
        sHs[tid]       = ws[WS_HSTAT + b*512 + tid]       + ws[WS_HSTATB + b*512 + tid];
        sHs[tid + 256] = ws[WS_HSTAT + b*512 + tid + 256] + ws[WS_HSTATB + b*512 + tid + 256];
    }
    int tv = t_arr[b];
    float ab = ws[WS_ALPHAS + tv];
    float sa = sqrtf(ab), sb = sqrtf(1.0f - ab);
    {   // stage 32 rows x 64 cols
        int r = tid >> 3, c0 = (tid & 7) * 8;
        const f32x4* pf = (const f32x4*)&fut[((size_t)b*64 + tf0 + r)*64 + c0];
        const f32x4* pe = (const f32x4*)&eps[((size_t)b*64 + tf0 + r)*64 + c0];
        f32x4 f0 = pf[0], f1 = pf[1], e0 = pe[0], e1 = pe[1];
        u16x4 p0, p1;
        p0.x = f2bf(sa*f0.x + sb*e0.x); p0.y = f2bf(sa*f0.y + sb*e0.y);
        p0.z = f2bf(sa*f0.z + sb*e0.z); p0.w = f2bf(sa*f0.w + sb*e0.w);
        p1.x = f2bf(sa*f1.x + sb*e1.x); p1.y = f2bf(sa*f1.y + sb*e1.y);
        p1.z = f2bf(sa*f1.z + sb*e1.z); p1.w = f2bf(sa*f1.w + sb*e1.w);
        *(u16x4*)&sN[r*PADN + c0]     = p0;
        *(u16x4*)&sN[r*PADN + c0 + 4] = p1;
    }
    __syncthreads();
    int w = tid >> 6, l = tid & 63, lr = l & 15, lk = (l >> 4) * 8;
    const u16* w1T = uws + U_W1T;
    const u16* w2T = uws + U_W2T;
    // h-head: wave w owns j in [w*128, w*128+128) (8 mt tiles); nb preloaded;
    // 2-deep pipeline on the global aw loads
    s16x8 nb[2][2];
    #pragma unroll
    for(int nt = 0; nt < 2; nt++){
        nb[nt][0] = *(const s16x8*)&sN[(nt*16 + lr)*PADN + lk];
        nb[nt][1] = *(const s16x8*)&sN[(nt*16 + lr)*PADN + 32 + lk];
    }
    const u16* w1base = &w1T[((size_t)e*512 + w*128 + lr)*1088 + lk];
    s16x8 aw0 = *(const s16x8*)(w1base);
    s16x8 aw1 = *(const s16x8*)(w1base + 32);
    for(int mt = 0; mt < 8; mt++){
        int nmt = (mt + 1) & 7;
        s16x8 nw0 = *(const s16x8*)(w1base + (size_t)nmt*16*1088);
        s16x8 nw1 = *(const s16x8*)(w1base + (size_t)nmt*16*1088 + 32);
        int j0 = w*128 + mt*16 + (l >> 4)*4;
        f32x4 hsv = *(const f32x4*)&sHs[j0];
        #pragma unroll
        for(int nt = 0; nt < 2; nt++){
            f32x4 acc = hsv;
            mfma16(acc, aw0, nb[nt][0]);
            mfma16(acc, aw1, nb[nt][1]);
            u16x4 pk;
            pk.x = f2bf(gelu_f(acc.x)); pk.y = f2bf(gelu_f(acc.y));
            pk.z = f2bf(gelu_f(acc.z)); pk.w = f2bf(gelu_f(acc.w));
            *(u16x4*)&sH[(nt*16 + lr)*PADH + j0] = pk;
        }
        aw0 = nw0; aw1 = nw1;
    }
    __syncthreads();
    // out: out[32 tf][64 f], K=512; wave w -> nt_o = w, mt_o in {0,1}
    int nt_o = w;
    f32x4 oacc[2];
    {
        float bz = b2[e*64 + nt_o*16 + lr];
        f32x4 z = {bz, bz, bz, bz}; oacc[0] = z; oacc[1] = z;
    }
    #pragma unroll 4
    for(int ks = 0; ks < 16; ks++){
        s16x8 bb = *(const s16x8*)&w2T[((size_t)e*64 + nt_o*16 + lr)*512 + ks*32 + lk];
        #pragma unroll
        for(int i = 0; i < 2; i++){
            s16x8 a = *(const s16x8*)&sH[(i*16 + lr)*PADH + ks*32 + lk];
            mfma16(oacc[i], a, bb);
        }
    }
    if(store){
        #pragma unroll
        for(int i = 0; i < 2; i++)
            #pragma unroll
            for(int rg = 0; rg < 4; rg++){
                int row = tf0 + i*16 + (l >> 4)*4 + rg;
                int col = nt_o*16 + lr;
                ws[WS_OUTSUB + (e*4 + b)*4096 + row*64 + col] = oacc[i][rg];
            }
    } else {
        float ls = 0.f;
        #pragma unroll
        for(int i = 0; i < 2; i++)
            #pragma unroll
            for(int rg = 0; rg < 4; rg++){
                int row = tf0 + i*16 + (l >> 4)*4 + rg;
                int col = nt_o*16 + lr;
                float d = oacc[i][rg] - eps[((size_t)b*64 + row)*64 + col];
                ls += d*d;
            }
        #pragma unroll
        for(int off = 32; off > 0; off >>= 1) ls += __shfl_down(ls, off);
        if(l == 0) sRed[w] = ls;
        __syncthreads();
        if(tid == 0){
            float s = sRed[0] + sRed[1] + sRed[2] + sRed[3];
            ws[WS_LOSSB + half*512 + b] = s;   // raw; scaled+weighted in k5
        }
    }
}

// ---------------- k5: 52 partial blocks + atomic-join finalize ----------------
__global__ __launch_bounds__(256) void k5_final(float* __restrict__ ws, float* __restrict__ out){
    int bid = blockIdx.x, tid = threadIdx.x;
    int* wsi = (int*)ws;
    if(bid < 52){
        __shared__ float red[256];
        int part = bid >> 2, q = bid & 3;
        float s = 0.f;
        if(part < 7){
            const int pa[7] = {0,1,3,4,0,1,2};
            const int pb[7] = {1,2,4,5,3,4,5};
            const float* A  = &ws[WS_OUTSUB + pa[part]*16384];
            const float* Bp = &ws[WS_OUTSUB + pb[part]*16384];
            for(int i = q*1024 + tid; i < q*1024 + 1024; i += 256){
                f32x4 a = *(const f32x4*)&A[i*4];
                f32x4 c = *(const f32x4*)&Bp[i*4];
                f32x4 d = a - c;
                s += d.x*d.x + d.y*d.y + d.z*d.z + d.w*d.w;
            }
            s *= (1.0f/16384.0f);
        } else {
            int e = part - 7;
            const float* O = &ws[WS_OUTSUB + e*16384];
            for(int i = q*1008 + tid; i < q*1008 + 1008; i += 256){
                int sm = i / (63*16); int r = i % (63*16);
                int tf = r / 16; int f4 = (r % 16) * 4;
                f32x4 a = *(const f32x4*)&O[(sm*64 + tf + 1)*64 + f4];
                f32x4 c = *(const f32x4*)&O[(sm*64 + tf)*64 + f4];
                f32x4 d = a - c;
                s += d.x*d.x + d.y*d.y + d.z*d.z + d.w*d.w;
            }
            s *= (1.0f/16128.0f) * 0.5f;
        }
        red[tid] = s;
        __syncthreads();
        for(int st = 128; st > 0; st >>= 1){
            if(tid < st) red[tid] += red[tid + st];
            __syncthreads();
        }
        if(tid == 0){
            ws[WS_PARTS + bid] = red[0];
            __threadfence();
            atomicAdd(&wsi[WS_FLAG], 1);
        }
        return;
    }
    if(tid == 0){
        while(atomicAdd(&wsi[WS_FLAG], 0) < 52) __builtin_amdgcn_s_sleep(2);
    }
    __syncthreads();
    __threadfence();
    __shared__ float sW[4];
    __shared__ float sF[4][6], sP[4][6];
    int w = tid >> 6, l = tid & 63;
    int sel0 = wsi[WS_SELECTED + tid];
    int sel1 = wsi[WS_SELECTED + 256 + tid];
    float wg0 = (sel0 % 3 == 0) ? 1.f : 5.f;
    float wg1 = (sel1 % 3 == 0) ? 1.f : 5.f;
    float lv = (ws[WS_LOSSB + tid] + ws[WS_LOSSB + 512 + tid]) * (1.0f/4096.0f) * wg0
             + (ws[WS_LOSSB + 256 + tid] + ws[WS_LOSSB + 768 + tid]) * (1.0f/4096.0f) * wg1;
    float pv[6], cf[6];
    #pragma unroll
    for(int e = 0; e < 6; e++){
        pv[e] = ws[WS_PROBS + tid*6 + e] + ws[WS_PROBS + (256 + tid)*6 + e];
        cf[e] = ((sel0 == e) ? 1.f : 0.f) + ((sel1 == e) ? 1.f : 0.f);
    }
    #pragma unroll
    for(int off = 32; off > 0; off >>= 1){
        lv += __shfl_down(lv, off);
        #pragma unroll
        for(int e = 0; e < 6; e++){
            pv[e] += __shfl_down(pv[e], off);
            cf[e] += __shfl_down(cf[e], off);
        }
    }
    if(l == 0){
        sW[w] = lv;
        #pragma unroll
        for(int e = 0; e < 6; e++){ sF[w][e] = cf[e]; sP[w][e] = pv[e]; }
    }
    __syncthreads();
    if(tid == 0){
        float total = 0.f;
        for(int q = 0; q < 4; q++) total += sW[q];
        total *= (1.0f/512.0f);
        volatile float* vp = ws + WS_PARTS;
        float reg = 0.f;
        for(int p = 0; p < 52; p++) reg += vp[p];
        total += 0.01f * reg;
        float lb = 0.f;
        for(int e = 0; e < 6; e++){
            float f = 0.f, pp = 0.f;
            for(int q = 0; q < 4; q++){ f += sF[q][e]; pp += sP[q][e]; }
            lb += (f * (1.0f/512.f)) * (pp * (1.0f/512.f));
        }
        out[0] = total + 0.01f * 6.0f * lb;
    }
}

extern "C" void kernel_launch(void* const* d_in, const int* in_sizes, int n_in,
                              void* d_out, int out_size, void* d_ws, size_t ws_size,
                              hipStream_t stream){
    const float* obs  = (const float*)d_in[0];
    const float* fut  = (const float*)d_in[1];
    const float* stat = (const float*)d_in[2];
    const float* eps  = (const float*)d_in[3];
    const int*   phase= (const int*)d_in[4];
    const int*   t    = (const int*)d_in[5];
    const float* Wenc = (const float*)d_in[6];
    const float* benc = (const float*)d_in[7];
    const float* Wstat= (const float*)d_in[8];
    const float* Wr   = (const float*)d_in[9];
    const float* br   = (const float*)d_in[10];
    const float* W1   = (const float*)d_in[11];
    const float* b1   = (const float*)d_in[12];
    const float* W2   = (const float*)d_in[13];
    const float* b2   = (const float*)d_in[14];
    float* ws  = (float*)d_ws;
    u16*   uws = (u16*)((char*)d_ws + WS_U16BYTE);
    float* out = (float*)d_out;

    k0<<<937, 256, 0, stream>>>(Wenc, W1, W2, stat, Wstat, benc, uws, ws);
    k1_enc<<<512, 1024, 0, stream>>>(obs, uws, Wr, br, phase, t, ws);
    k3_hstat<<<224, 256, 0, stream>>>(uws, b1, ws);
    k4_ffn<<<1072, 256, 0, stream>>>(fut, eps, t, uws, b2, ws);
    k5_final<<<53, 256, 0, stream>>>(ws, out);
}

// Round 19
// 96.035 us; speedup vs baseline: 1.0191x; 1.0191x over previous
//
#include <hip/hip_runtime.h>

typedef float  f32x4 __attribute__((ext_vector_type(4)));
typedef short  s16x8 __attribute__((ext_vector_type(8)));
typedef unsigned short u16;
typedef u16    u16x4 __attribute__((ext_vector_type(4)));
typedef u16    u16x8 __attribute__((ext_vector_type(8)));

#define TIMESTEPS 1000

// ---- ws float-offset map ----
#define WS_ALPHAS   0        // 1000 f
#define WS_FREQS    1024     // 256 f
#define WS_PROBS    1536     // 512*6 f
#define WS_SELECTED 4608     // 512 int
#define WS_LOSSB    5632     // 1024 f (raw sums; [half*512+b], written once each)
#define WS_PARTS    7680     // 52 f
#define WS_FLAG     7744     // 1 int (k5 join; reset by k3 block 0)
#define WS_HSTATB   8192     // 512*512 f (K-half-1 of hstat)
#define WS_XC       270336   // 512*1024 bf16 (u16)
#define WS_HSTAT    532480   // 512*512 f (K-half-0 of hstat)
#define WS_HSTAT2   794624   // 6*4*512 f (aux half-0)
#define WS_OUTSUB   806912   // 6*4*64*64 f
#define WS_BIAS     2691072  // 512*512 f = bytes [10764288, 11812864)
#define WS_HSTAT2B  2691072  // 6*4*512 f (aux half-1; reuses BIAS head after k1)
#define WS_U16BYTE  3620864  // byte offset of u16 weight region
// u16-offsets inside u16 region (region bytes [3620864, ...))
#define U_WENCT     0        // 512*64
#define U_W1T       32768    // 6*512*1088   -> ends 3375104
#define U_W2T       3375104  // 6*64*512     -> ends 3571712 (byte 10764288 = WS_BIAS)
#define U_XB        4096000  // 512*256*64 bf16, bytes [11812864, 28590080) - after BIAS

__device__ __forceinline__ u16 f2bf(float x){
    unsigned u = __builtin_bit_cast(unsigned, x);
    unsigned r = (u + 0x7FFFu + ((u >> 16) & 1u)) >> 16;
    return (u16)r;
}

// exp2-based tanh-gelu: gelu = x - x/(exp2(x*(a*x^2+b)) + 1), a,b pre-scaled by 2/ln2.
__device__ __forceinline__ float gelu_f(float x){
    float arg = x * fmaf(0.102939240f, x*x, 2.302032318f);
    float ex  = __builtin_amdgcn_exp2f(arg);
    float r   = __builtin_amdgcn_rcpf(ex + 1.0f);
    return fmaf(-x, r, x);
}

__device__ __forceinline__ void mfma16(f32x4& c, s16x8 a, s16x8 b){
    asm volatile("v_mfma_f32_16x16x32_bf16 %0, %1, %2, %0" : "+v"(c) : "v"(a), "v"(b));
}

// ---------------- k0: init + bias table + transposes + obs->bf16 prestage ----------------
__global__ __launch_bounds__(256) void k0(const float* __restrict__ Wenc,
        const float* __restrict__ W1, const float* __restrict__ W2,
        const float* __restrict__ stat, const float* __restrict__ Wstat,
        const float* __restrict__ benc, const float* __restrict__ obs,
        u16* __restrict__ uws, float* __restrict__ ws){
    __shared__ float sT[64][65];
    float* sp = &sT[0][0];
    int bid = blockIdx.x, tid = threadIdx.x;
    if(bid == 0){
        ws[WS_FREQS + tid] = expf(-logf(10000.0f) * (float)tid / 256.0f);
        float p = 1.f;
        #pragma unroll
        for(int r = 0; r < 4; r++){
            int i = tid*4 + r;
            if(i < TIMESTEPS){
                float beta = 0.0001f + (0.02f - 0.0001f) * ((float)i / 999.0f);
                p *= (1.0f - beta);
            }
        }
        sp[tid] = p;
        __syncthreads();
        for(int st = 1; st < 256; st <<= 1){
            float v = (tid >= st) ? sp[tid - st] : 1.0f;
            __syncthreads();
            sp[tid] *= v;
            __syncthreads();
        }
        float run = (tid == 0) ? 1.0f : sp[tid - 1];
        for(int r = 0; r < 4; r++){
            int i = tid*4 + r;
            if(i < TIMESTEPS){
                float beta = 0.0001f + (0.02f - 0.0001f) * ((float)i / 999.0f);
                run *= (1.0f - beta);
                ws[WS_ALPHAS + i] = run;
            }
        }
        return;
    }
    if(bid >= 937){
        // obs -> bf16 prestage: one block per sample
        int g = bid - 937;
        const float* src = obs + (size_t)g*16384;
        u16* dst = uws + U_XB + (size_t)g*16384;
        #pragma unroll 4
        for(int i = 0; i < 16; i++){
            int idx = i*1024 + tid*4;
            f32x4 v = *(const f32x4*)&src[idx];
            u16x4 pk; pk.x = f2bf(v.x); pk.y = f2bf(v.y); pk.z = f2bf(v.z); pk.w = f2bf(v.w);
            *(u16x4*)&dst[idx] = pk;
        }
        return;
    }
    if(bid <= 8){
        int jt = bid - 1;
        int r = tid >> 2, c0 = (tid & 3) * 16;
        #pragma unroll
        for(int i = 0; i < 4; i++)
            *(f32x4*)&sT[r][c0 + i*4] = *(const f32x4*)&Wenc[(size_t)r*512 + jt*64 + c0 + i*4];
        __syncthreads();
        u16* dst = uws + U_WENCT + (size_t)(jt*64 + r)*64;
        #pragma unroll
        for(int i = 0; i < 4; i++){
            u16x4 pk;
            pk.x = f2bf(sT[c0 + i*4 + 0][r]); pk.y = f2bf(sT[c0 + i*4 + 1][r]);
            pk.z = f2bf(sT[c0 + i*4 + 2][r]); pk.w = f2bf(sT[c0 + i*4 + 3][r]);
            *(u16x4*)&dst[c0 + i*4] = pk;
        }
        return;
    }
    if(bid <= 72){
        float* sSt = sp;
        int g = bid - 9, b0 = g*8;
        sSt[tid] = stat[b0*32 + tid];
        __syncthreads();
        #pragma unroll
        for(int half = 0; half < 2; half++){
            int j = tid + half*256;
            float acc[8] = {0,0,0,0,0,0,0,0};
            for(int s = 0; s < 32; s++){
                float wv = Wstat[s*512 + j];
                #pragma unroll
                for(int bb = 0; bb < 8; bb++) acc[bb] += sSt[bb*32 + s] * wv;
            }
            float bz = benc[j];
            #pragma unroll
            for(int bb = 0; bb < 8; bb++)
                ws[WS_BIAS + (b0 + bb)*512 + j] = acc[bb] + bz;
        }
        return;
    }
    int t = bid - 73;
    const float* src; u16* dst; int K, J, kt, jt;
    if(t < 816){
        int e = t / 136, r = t % 136; kt = r >> 3; jt = r & 7;
        src = W1 + (size_t)e*1088*512; dst = uws + U_W1T + (size_t)e*512*1088; K = 1088; J = 512;
    } else {
        int t2 = t - 816; int e = t2 >> 3; kt = t2 & 7; jt = 0;
        src = W2 + (size_t)e*512*64; dst = uws + U_W2T + (size_t)e*64*512; K = 512; J = 64;
    }
    int r = tid >> 2, c0 = (tid & 3) * 16;
    #pragma unroll
    for(int i = 0; i < 4; i++)
        *(f32x4*)&sT[r][c0 + i*4] = *(const f32x4*)&src[(size_t)(kt*64 + r)*J + jt*64 + c0 + i*4];
    __syncthreads();
    u16* d2 = dst + (size_t)(jt*64 + r)*K + kt*64;
    #pragma unroll
    for(int i = 0; i < 4; i++){
        u16x4 pk;
        pk.x = f2bf(sT[c0 + i*4 + 0][r]); pk.y = f2bf(sT[c0 + i*4 + 1][r]);
        pk.z = f2bf(sT[c0 + i*4 + 2][r]); pk.w = f2bf(sT[c0 + i*4 + 3][r]);
        *(u16x4*)&d2[c0 + i*4] = pk;
    }
}

// ---------------- k1: encoder + router, 1024 threads, bf16 prestaged input --------
#define PADX 72
__global__ __launch_bounds__(1024) void k1_enc(
        const u16* __restrict__ uws, const float* __restrict__ Wr,
        const float* __restrict__ br, const int* __restrict__ phase,
        const int* __restrict__ t_arr, float* __restrict__ ws){
    __shared__ u16  sX[256 * PADX];
    __shared__ float sBias[512];
    __shared__ float sG[512];
    __shared__ float sRed[8][6];
    int b = blockIdx.x, tid = threadIdx.x;
    {   // stage pre-converted bf16: 2 x 16B load + 2 x b128 LDS write per thread
        int row = tid >> 2, c0 = (tid & 3) * 16;
        const u16* src = uws + U_XB + ((size_t)b*256 + row)*64 + c0;
        u16* dst = &sX[row*PADX + c0];
        *(u16x8*)(dst)     = *(const u16x8*)(src);
        *(u16x8*)(dst + 8) = *(const u16x8*)(src + 8);
    }
    if(tid < 512) sBias[tid] = ws[WS_BIAS + b*512 + tid];
    __syncthreads();
    int w = tid >> 6, l = tid & 63, lr = l & 15, lk = (l >> 4) * 8;
    const u16* wencT = uws + U_WENCT;
    s16x8 bf[2][2];
    float bias[2];
    #pragma unroll
    for(int n = 0; n < 2; n++){
        int col = w*32 + n*16 + lr;
        bf[n][0] = *(const s16x8*)&wencT[col*64 + lk];
        bf[n][1] = *(const s16x8*)&wencT[col*64 + 32 + lk];
        bias[n]  = sBias[col];
    }
    float cac[2] = {0.f, 0.f};
    for(int mt = 0; mt < 16; mt++){
        s16x8 a0 = *(const s16x8*)&sX[(mt*16 + lr)*PADX + lk];
        s16x8 a1 = *(const s16x8*)&sX[(mt*16 + lr)*PADX + 32 + lk];
        #pragma unroll
        for(int n = 0; n < 2; n++){
            f32x4 acc = {bias[n], bias[n], bias[n], bias[n]};
            mfma16(acc, a0, bf[n][0]);
            mfma16(acc, a1, bf[n][1]);
            cac[n] += gelu_f(acc.x) + gelu_f(acc.y) + gelu_f(acc.z) + gelu_f(acc.w);
        }
    }
    #pragma unroll
    for(int n = 0; n < 2; n++){
        cac[n] += __shfl_xor(cac[n], 16);
        cac[n] += __shfl_xor(cac[n], 32);
    }
    if(l < 16){
        #pragma unroll
        for(int n = 0; n < 2; n++)
            sG[w*32 + n*16 + l] = cac[n] * (1.0f/256.0f);
    }
    __syncthreads();
    if(tid < 512){
        float gv = sG[tid];
        u16* XC = (u16*)(ws + WS_XC);
        XC[b*1024 + tid] = f2bf(gv);
        int tv = t_arr[b];
        float fr = ws[WS_FREQS + (tid & 255)];
        float ang = (float)tv * fr;
        XC[b*1024 + 512 + tid] = f2bf((tid < 256) ? sinf(ang) : cosf(ang));
        float p6[6];
        #pragma unroll
        for(int e = 0; e < 6; e++) p6[e] = gv * Wr[tid*6 + e];
        #pragma unroll
        for(int off = 32; off > 0; off >>= 1)
            #pragma unroll
            for(int e = 0; e < 6; e++) p6[e] += __shfl_down(p6[e], off);
        if(l == 0)
            #pragma unroll
            for(int e = 0; e < 6; e++) sRed[w][e] = p6[e];
    }
    __syncthreads();
    if(tid == 0){
        float logit[6], mx = -1e30f;
        #pragma unroll
        for(int e = 0; e < 6; e++){
            float s = 0.f;
            #pragma unroll
            for(int q = 0; q < 8; q++) s += sRed[q][e];
            logit[e] = s + br[e];
            mx = fmaxf(mx, logit[e]);
        }
        float s = 0.f, p[6];
        #pragma unroll
        for(int e = 0; e < 6; e++){
            p[e] = __builtin_amdgcn_exp2f((logit[e] - mx) * 1.44269504f);
            s += p[e];
        }
        float inv = 1.0f / s;
        #pragma unroll
        for(int e = 0; e < 6; e++) ws[WS_PROBS + b*6 + e] = p[e] * inv;
        int ph = phase[b];
        int sel = ph + ((logit[ph + 3] > logit[ph]) ? 3 : 0);
        ((int*)ws)[WS_SELECTED + b] = sel;
    }
}

// ---------------- k3: hstat GEMM, K-split x2 (grid 224 = 14 chunks x 8 jt x 2 kh) --------
__global__ __launch_bounds__(256) void k3_hstat(const u16* __restrict__ uws,
        const float* __restrict__ b1, float* __restrict__ ws){
    __shared__ int sSrc[64], sDst[64];
    __shared__ int sCnt[8][6], sBase[8][6], sSec[6], sTot[6];
    __shared__ int sChunk[16][3];
    __shared__ int sNch;
    int bid = blockIdx.x, tid = threadIdx.x;
    int w = tid >> 6, l = tid & 63;
    int* wsi = (int*)ws;
    if(bid == 0 && tid == 0) wsi[WS_FLAG] = 0;   // reset k5 join counter
    int kh = bid & 1, jt = (bid >> 1) & 7, c = bid >> 4;
    int sv0 = wsi[WS_SELECTED + tid];
    int sv1 = wsi[WS_SELECTED + 256 + tid];
    unsigned long long mym0 = 0, mym1 = 0;
    #pragma unroll
    for(int e = 0; e < 6; e++){
        unsigned long long m0 = __ballot(sv0 == e);
        unsigned long long m1 = __ballot(sv1 == e);
        if(l == 0){ sCnt[w][e] = __popcll(m0); sCnt[4 + w][e] = __popcll(m1); }
        if(sv0 == e) mym0 = m0;
        if(sv1 == e) mym1 = m1;
    }
    if(tid < 64){ sSrc[tid] = 0; sDst[tid] = -1; }
    __syncthreads();
    if(tid == 0){
        int o = 0;
        for(int e = 0; e < 6; e++){
            sSec[e] = o; int t0 = 0;
            for(int g = 0; g < 8; g++){ sBase[g][e] = o; o += sCnt[g][e]; t0 += sCnt[g][e]; }
            sTot[e] = t0; o += 4;
        }
        int nch = 0;
        for(int e = 0; e < 6; e++){
            int len = sTot[e] + 4, st = sSec[e];
            for(int s = 0; s < len; s += 64){
                sChunk[nch][0] = e; sChunk[nch][1] = st + s;
                sChunk[nch][2] = (len - s < 64) ? (len - s) : 64; nch++;
            }
        }
        sNch = nch;
    }
    __syncthreads();
    if(c >= sNch) return;
    int e     = sChunk[c][0];
    int start = sChunk[c][1];
    int len   = sChunk[c][2];
    int hstatD  = kh ? WS_HSTATB  : WS_HSTAT;
    int hstat2D = kh ? WS_HSTAT2B : WS_HSTAT2;
    {
        int rank = __popcll(mym0 & ((1ull << l) - 1ull));
        int pos = sBase[w][sv0] + rank - start;
        if(pos >= 0 && pos < len){ sSrc[pos] = tid; sDst[pos] = hstatD + tid*512; }
    }
    {
        int rank = __popcll(mym1 & ((1ull << l) - 1ull));
        int pos = sBase[4 + w][sv1] + rank - start;
        if(pos >= 0 && pos < len){ sSrc[pos] = 256 + tid; sDst[pos] = hstatD + (256 + tid)*512; }
    }
    if(tid < 24){
        int ea = tid >> 2, ba = tid & 3;
        int pos = sSec[ea] + sTot[ea] + ba - start;
        if(pos >= 0 && pos < len){ sSrc[pos] = ba; sDst[pos] = hstat2D + (ea*4 + ba)*512; }
    }
    __syncthreads();
    int lr = l & 15, lk = (l >> 4) * 8;
    int col = jt*64 + w*16 + lr;
    const u16* XC = (const u16*)(ws + WS_XC);
    const u16* rowA[4];
    #pragma unroll
    for(int mt = 0; mt < 4; mt++)
        rowA[mt] = XC + (size_t)sSrc[mt*16 + lr]*1024 + kh*512 + lk;
    const u16* bp = uws + U_W1T + ((size_t)e*512 + col)*1088 + 64 + kh*512 + lk;
    f32x4 acc[4];
    {
        float bv = kh ? 0.f : b1[e*512 + col];
        f32x4 z = {bv, bv, bv, bv};
        #pragma unroll
        for(int mt = 0; mt < 4; mt++) acc[mt] = z;
    }
    #pragma unroll 4
    for(int ks = 0; ks < 16; ks++){
        s16x8 bb = *(const s16x8*)(bp + ks*32);
        s16x8 a0 = *(const s16x8*)(rowA[0] + ks*32);
        s16x8 a1 = *(const s16x8*)(rowA[1] + ks*32);
        s16x8 a2 = *(const s16x8*)(rowA[2] + ks*32);
        s16x8 a3 = *(const s16x8*)(rowA[3] + ks*32);
        mfma16(acc[0], a0, bb);
        mfma16(acc[1], a1, bb);
        mfma16(acc[2], a2, bb);
        mfma16(acc[3], a3, bb);
    }
    #pragma unroll
    for(int mt = 0; mt < 4; mt++){
        #pragma unroll
        for(int rg = 0; rg < 4; rg++){
            int r = mt*16 + (l >> 4)*4 + rg;
            int d = sDst[r];
            if(d >= 0) ws[d + col] = acc[mt][rg];
        }
    }
}

// ---------------- k4: FFN, 256 thr, 32-tf halves (grid 1072), 4 blocks/CU ----------------
#define PADN 72
#define PADH 520
__global__ __launch_bounds__(256) void k4_ffn(const float* __restrict__ fut,
        const float* __restrict__ eps, const int* __restrict__ t_arr,
        const u16* __restrict__ uws, const float* __restrict__ b2,
        float* __restrict__ ws){
    __shared__ u16 sN[32 * PADN];
    __shared__ u16 sH[32 * PADH];    // [tf][j]
    __shared__ float sHs[512];
    __shared__ float sRed[4];
    int tid = threadIdx.x, bid = blockIdx.x;
    int* wsi = (int*)ws;
    int b, e, store, half;
    if(bid < 48){ int idx = bid >> 1; half = bid & 1; e = idx >> 2; b = idx & 3; store = 1; }
    else { int r = bid - 48; b = r >> 1; half = r & 1; e = wsi[WS_SELECTED + b]; store = 0; }
    int tf0 = half * 32;
    if(store){
        int i2 = (e*4 + b)*512;
        sHs[tid]       = ws[WS_HSTAT2 + i2 + tid]       + ws[WS_HSTAT2B + i2 + tid];
        sHs[tid + 256] = ws[WS_HSTAT2 + i2 + tid + 256] + ws[WS_HSTAT2B + i2 + tid + 256];
    } else {
        sHs[tid]       = ws[WS_HSTAT + b*512 + tid]       + ws[WS_HSTATB + b*512 + tid];
        sHs[tid + 256] = ws[WS_HSTAT + b*512 + tid + 256] + ws[WS_HSTATB + b*512 + tid + 256];
    }
    int tv = t_arr[b];
    float ab = ws[WS_ALPHAS + tv];
    float sa = sqrtf(ab), sb = sqrtf(1.0f - ab);
    {   // stage 32 rows x 64 cols
        int r = tid >> 3, c0 = (tid & 7) * 8;
        const f32x4* pf = (const f32x4*)&fut[((size_t)b*64 + tf0 + r)*64 + c0];
        const f32x4* pe = (const f32x4*)&eps[((size_t)b*64 + tf0 + r)*64 + c0];
        f32x4 f0 = pf[0], f1 = pf[1], e0 = pe[0], e1 = pe[1];
        u16x4 p0, p1;
        p0.x = f2bf(sa*f0.x + sb*e0.x); p0.y = f2bf(sa*f0.y + sb*e0.y);
        p0.z = f2bf(sa*f0.z + sb*e0.z); p0.w = f2bf(sa*f0.w + sb*e0.w);
        p1.x = f2bf(sa*f1.x + sb*e1.x); p1.y = f2bf(sa*f1.y + sb*e1.y);
        p1.z = f2bf(sa*f1.z + sb*e1.z); p1.w = f2bf(sa*f1.w + sb*e1.w);
        *(u16x4*)&sN[r*PADN + c0]     = p0;
        *(u16x4*)&sN[r*PADN + c0 + 4] = p1;
    }
    __syncthreads();
    int w = tid >> 6, l = tid & 63, lr = l & 15, lk = (l >> 4) * 8;
    const u16* w1T = uws + U_W1T;
    const u16* w2T = uws + U_W2T;
    s16x8 nb[2][2];
    #pragma unroll
    for(int nt = 0; nt < 2; nt++){
        nb[nt][0] = *(const s16x8*)&sN[(nt*16 + lr)*PADN + lk];
        nb[nt][1] = *(const s16x8*)&sN[(nt*16 + lr)*PADN + 32 + lk];
    }
    #pragma unroll
    for(int mt = 0; mt < 8; mt++){
        int jrow = w*128 + mt*16 + lr;
        s16x8 aw0 = *(const s16x8*)&w1T[((size_t)e*512 + jrow)*1088 + lk];
        s16x8 aw1 = *(const s16x8*)&w1T[((size_t)e*512 + jrow)*1088 + 32 + lk];
        int j0 = w*128 + mt*16 + (l >> 4)*4;
        f32x4 hsv = *(const f32x4*)&sHs[j0];
        #pragma unroll
        for(int nt = 0; nt < 2; nt++){
            f32x4 acc = hsv;
            mfma16(acc, aw0, nb[nt][0]);
            mfma16(acc, aw1, nb[nt][1]);
            u16x4 pk;
            pk.x = f2bf(gelu_f(acc.x)); pk.y = f2bf(gelu_f(acc.y));
            pk.z = f2bf(gelu_f(acc.z)); pk.w = f2bf(gelu_f(acc.w));
            *(u16x4*)&sH[(nt*16 + lr)*PADH + j0] = pk;
        }
    }
    __syncthreads();
    int nt_o = w;
    f32x4 oacc[2];
    {
        float bz = b2[e*64 + nt_o*16 + lr];
        f32x4 z = {bz, bz, bz, bz}; oacc[0] = z; oacc[1] = z;
    }
    for(int ks = 0; ks < 16; ks++){
        s16x8 bb = *(const s16x8*)&w2T[((size_t)e*64 + nt_o*16 + lr)*512 + ks*32 + lk];
        #pragma unroll
        for(int i = 0; i < 2; i++){
            s16x8 a = *(const s16x8*)&sH[(i*16 + lr)*PADH + ks*32 + lk];
            mfma16(oacc[i], a, bb);
        }
    }
    if(store){
        #pragma unroll
        for(int i = 0; i < 2; i++)
            #pragma unroll
            for(int rg = 0; rg < 4; rg++){
                int row = tf0 + i*16 + (l >> 4)*4 + rg;
                int col = nt_o*16 + lr;
                ws[WS_OUTSUB + (e*4 + b)*4096 + row*64 + col] = oacc[i][rg];
            }
    } else {
        float ls = 0.f;
        #pragma unroll
        for(int i = 0; i < 2; i++)
            #pragma unroll
            for(int rg = 0; rg < 4; rg++){
                int row = tf0 + i*16 + (l >> 4)*4 + rg;
                int col = nt_o*16 + lr;
                float d = oacc[i][rg] - eps[((size_t)b*64 + row)*64 + col];
                ls += d*d;
            }
        #pragma unroll
        for(int off = 32; off > 0; off >>= 1) ls += __shfl_down(ls, off);
        if(l == 0) sRed[w] = ls;
        __syncthreads();
        if(tid == 0){
            float s = sRed[0] + sRed[1] + sRed[2] + sRed[3];
            ws[WS_LOSSB + half*512 + b] = s;   // raw; scaled+weighted in k5
        }
    }
}

// ---------------- k5: 52 partial blocks + atomic-join finalize ----------------
__global__ __launch_bounds__(256) void k5_final(float* __restrict__ ws, float* __restrict__ out){
    int bid = blockIdx.x, tid = threadIdx.x;
    int* wsi = (int*)ws;
    if(bid < 52){
        __shared__ float red[256];
        int part = bid >> 2, q = bid & 3;
        float s = 0.f;
        if(part < 7){
            const int pa[7] = {0,1,3,4,0,1,2};
            const int pb[7] = {1,2,4,5,3,4,5};
            const float* A  = &ws[WS_OUTSUB + pa[part]*16384];
            const float* Bp = &ws[WS_OUTSUB + pb[part]*16384];
            for(int i = q*1024 + tid; i < q*1024 + 1024; i += 256){
                f32x4 a = *(const f32x4*)&A[i*4];
                f32x4 c = *(const f32x4*)&Bp[i*4];
                f32x4 d = a - c;
                s += d.x*d.x + d.y*d.y + d.z*d.z + d.w*d.w;
            }
            s *= (1.0f/16384.0f);
        } else {
            int e = part - 7;
            const float* O = &ws[WS_OUTSUB + e*16384];
            for(int i = q*1008 + tid; i < q*1008 + 1008; i += 256){
                int sm = i / (63*16); int r = i % (63*16);
                int tf = r / 16; int f4 = (r % 16) * 4;
                f32x4 a = *(const f32x4*)&O[(sm*64 + tf + 1)*64 + f4];
                f32x4 c = *(const f32x4*)&O[(sm*64 + tf)*64 + f4];
                f32x4 d = a - c;
                s += d.x*d.x + d.y*d.y + d.z*d.z + d.w*d.w;
            }
            s *= (1.0f/16128.0f) * 0.5f;
        }
        red[tid] = s;
        __syncthreads();
        for(int st = 128; st > 0; st >>= 1){
            if(tid < st) red[tid] += red[tid + st];
            __syncthreads();
        }
        if(tid == 0){
            ws[WS_PARTS + bid] = red[0];
            __threadfence();
            atomicAdd(&wsi[WS_FLAG], 1);
        }
        return;
    }
    if(tid == 0){
        while(atomicAdd(&wsi[WS_FLAG], 0) < 52) __builtin_amdgcn_s_sleep(2);
    }
    __syncthreads();
    __threadfence();
    __shared__ float sW[4];
    __shared__ float sF[4][6], sP[4][6];
    int w = tid >> 6, l = tid & 63;
    int sel0 = wsi[WS_SELECTED + tid];
    int sel1 = wsi[WS_SELECTED + 256 + tid];
    float wg0 = (sel0 % 3 == 0) ? 1.f : 5.f;
    float wg1 = (sel1 % 3 == 0) ? 1.f : 5.f;
    float lv = (ws[WS_LOSSB + tid] + ws[WS_LOSSB + 512 + tid]) * (1.0f/4096.0f) * wg0
             + (ws[WS_LOSSB + 256 + tid] + ws[WS_LOSSB + 768 + tid]) * (1.0f/4096.0f) * wg1;
    float pv[6], cf[6];
    #pragma unroll
    for(int e = 0; e < 6; e++){
        pv[e] = ws[WS_PROBS + tid*6 + e] + ws[WS_PROBS + (256 + tid)*6 + e];
        cf[e] = ((sel0 == e) ? 1.f : 0.f) + ((sel1 == e) ? 1.f : 0.f);
    }
    #pragma unroll
    for(int off = 32; off > 0; off >>= 1){
        lv += __shfl_down(lv, off);
        #pragma unroll
        for(int e = 0; e < 6; e++){
            pv[e] += __shfl_down(pv[e], off);
            cf[e] += __shfl_down(cf[e], off);
        }
    }
    if(l == 0){
        sW[w] = lv;
        #pragma unroll
        for(int e = 0; e < 6; e++){ sF[w][e] = cf[e]; sP[w][e] = pv[e]; }
    }
    __syncthreads();
    if(tid == 0){
        float total = 0.f;
        for(int q = 0; q < 4; q++) total += sW[q];
        total *= (1.0f/512.0f);
        volatile float* vp = ws + WS_PARTS;
        float reg = 0.f;
        for(int p = 0; p < 52; p++) reg += vp[p];
        total += 0.01f * reg;
        float lb = 0.f;
        for(int e = 0; e < 6; e++){
            float f = 0.f, pp = 0.f;
            for(int q = 0; q < 4; q++){ f += sF[q][e]; pp += sP[q][e]; }
            lb += (f * (1.0f/512.f)) * (pp * (1.0f/512.f));
        }
        out[0] = total + 0.01f * 6.0f * lb;
    }
}

extern "C" void kernel_launch(void* const* d_in, const int* in_sizes, int n_in,
                              void* d_out, int out_size, void* d_ws, size_t ws_size,
                              hipStream_t stream){
    const float* obs  = (const float*)d_in[0];
    const float* fut  = (const float*)d_in[1];
    const float* stat = (const float*)d_in[2];
    const float* eps  = (const float*)d_in[3];
    const int*   phase= (const int*)d_in[4];
    const int*   t    = (const int*)d_in[5];
    const float* Wenc = (const float*)d_in[6];
    const float* benc = (const float*)d_in[7];
    const float* Wstat= (const float*)d_in[8];
    const float* Wr   = (const float*)d_in[9];
    const float* br   = (const float*)d_in[10];
    const float* W1   = (const float*)d_in[11];
    const float* b1   = (const float*)d_in[12];
    const float* W2   = (const float*)d_in[13];
    const float* b2   = (const float*)d_in[14];
    float* ws  = (float*)d_ws;
    u16*   uws = (u16*)((char*)d_ws + WS_U16BYTE);
    float* out = (float*)d_out;

    k0<<<1449, 256, 0, stream>>>(Wenc, W1, W2, stat, Wstat, benc, obs, uws, ws);
    k1_enc<<<512, 1024, 0, stream>>>(uws, Wr, br, phase, t, ws);
    k3_hstat<<<224, 256, 0, stream>>>(uws, b1, ws);
    k4_ffn<<<1072, 256, 0, stream>>>(fut, eps, t, uws, b2, ws);
    k5_final<<<53, 256, 0, stream>>>(ws, out);
}

// Round 20
// 93.760 us; speedup vs baseline: 1.0438x; 1.0243x over previous
//
#include <hip/hip_runtime.h>

typedef float  f32x4 __attribute__((ext_vector_type(4)));
typedef short  s16x8 __attribute__((ext_vector_type(8)));
typedef unsigned short u16;
typedef u16    u16x4 __attribute__((ext_vector_type(4)));

#define TIMESTEPS 1000

// ---- ws float-offset map ----
#define WS_ALPHAS   0        // 1000 f
#define WS_FREQS    1024     // 256 f
#define WS_PROBS    1536     // 512*6 f
#define WS_SELECTED 4608     // 512 int
#define WS_LOSSB    5632     // 1024 f (raw sums; [half*512+b], written once each)
#define WS_PARTS    7680     // 52 f
#define WS_FLAG     7744     // 1 int (k5 join; reset by k3 block 0)
#define WS_HSTATB   8192     // 512*512 f (K-half-1 of hstat)
#define WS_XC       270336   // 512*1024 bf16 (u16)
#define WS_HSTAT    532480   // 512*512 f (K-half-0 of hstat)
#define WS_HSTAT2   794624   // 6*4*512 f (aux half-0)
#define WS_OUTSUB   806912   // 6*4*64*64 f
#define WS_BIAS     2691072  // 512*512 f (k1 input; k3 reuses head as HSTAT2B)
#define WS_HSTAT2B  2691072  // 6*4*512 f (aux half-1; reuses BIAS after k1)
#define WS_U16BYTE  3620864  // byte offset of u16 weight region
// u16-offsets inside u16 region
#define U_WENCT     0        // 512*64
#define U_W1T       32768    // 6*512*1088
#define U_W2T       3375104  // 6*64*512

__device__ __forceinline__ u16 f2bf(float x){
    unsigned u = __builtin_bit_cast(unsigned, x);
    unsigned r = (u + 0x7FFFu + ((u >> 16) & 1u)) >> 16;
    return (u16)r;
}

// exp2-based tanh-gelu: gelu = x - x/(exp2(x*(a*x^2+b)) + 1), a,b pre-scaled by 2/ln2.
__device__ __forceinline__ float gelu_f(float x){
    float arg = x * fmaf(0.102939240f, x*x, 2.302032318f);
    float ex  = __builtin_amdgcn_exp2f(arg);
    float r   = __builtin_amdgcn_rcpf(ex + 1.0f);
    return fmaf(-x, r, x);
}

__device__ __forceinline__ void mfma16(f32x4& c, s16x8 a, s16x8 b){
    asm volatile("v_mfma_f32_16x16x32_bf16 %0, %1, %2, %0" : "+v"(c) : "v"(a), "v"(b));
}

// ---------------- k0: init + bias table + ALL transposes (64x64 tiles) ----------------
__global__ __launch_bounds__(256) void k0(const float* __restrict__ Wenc,
        const float* __restrict__ W1, const float* __restrict__ W2,
        const float* __restrict__ stat, const float* __restrict__ Wstat,
        const float* __restrict__ benc, u16* __restrict__ uws, float* __restrict__ ws){
    __shared__ float sT[64][65];
    float* sp = &sT[0][0];
    int bid = blockIdx.x, tid = threadIdx.x;
    if(bid == 0){
        ws[WS_FREQS + tid] = expf(-logf(10000.0f) * (float)tid / 256.0f);
        float p = 1.f;
        #pragma unroll
        for(int r = 0; r < 4; r++){
            int i = tid*4 + r;
            if(i < TIMESTEPS){
                float beta = 0.0001f + (0.02f - 0.0001f) * ((float)i / 999.0f);
                p *= (1.0f - beta);
            }
        }
        sp[tid] = p;
        __syncthreads();
        for(int st = 1; st < 256; st <<= 1){
            float v = (tid >= st) ? sp[tid - st] : 1.0f;
            __syncthreads();
            sp[tid] *= v;
            __syncthreads();
        }
        float run = (tid == 0) ? 1.0f : sp[tid - 1];
        for(int r = 0; r < 4; r++){
            int i = tid*4 + r;
            if(i < TIMESTEPS){
                float beta = 0.0001f + (0.02f - 0.0001f) * ((float)i / 999.0f);
                run *= (1.0f - beta);
                ws[WS_ALPHAS + i] = run;
            }
        }
        return;
    }
    if(bid <= 8){
        int jt = bid - 1;
        int r = tid >> 2, c0 = (tid & 3) * 16;
        #pragma unroll
        for(int i = 0; i < 4; i++)
            *(f32x4*)&sT[r][c0 + i*4] = *(const f32x4*)&Wenc[(size_t)r*512 + jt*64 + c0 + i*4];
        __syncthreads();
        u16* dst = uws + U_WENCT + (size_t)(jt*64 + r)*64;
        #pragma unroll
        for(int i = 0; i < 4; i++){
            u16x4 pk;
            pk.x = f2bf(sT[c0 + i*4 + 0][r]); pk.y = f2bf(sT[c0 + i*4 + 1][r]);
            pk.z = f2bf(sT[c0 + i*4 + 2][r]); pk.w = f2bf(sT[c0 + i*4 + 3][r]);
            *(u16x4*)&dst[c0 + i*4] = pk;
        }
        return;
    }
    if(bid <= 72){
        float* sSt = sp;
        int g = bid - 9, b0 = g*8;
        sSt[tid] = stat[b0*32 + tid];
        __syncthreads();
        #pragma unroll
        for(int half = 0; half < 2; half++){
            int j = tid + half*256;
            float acc[8] = {0,0,0,0,0,0,0,0};
            for(int s = 0; s < 32; s++){
                float wv = Wstat[s*512 + j];
                #pragma unroll
                for(int bb = 0; bb < 8; bb++) acc[bb] += sSt[bb*32 + s] * wv;
            }
            float bz = benc[j];
            #pragma unroll
            for(int bb = 0; bb < 8; bb++)
                ws[WS_BIAS + (b0 + bb)*512 + j] = acc[bb] + bz;
        }
        return;
    }
    int t = bid - 73;
    const float* src; u16* dst; int K, J, kt, jt;
    if(t < 816){
        int e = t / 136, r = t % 136; kt = r >> 3; jt = r & 7;
        src = W1 + (size_t)e*1088*512; dst = uws + U_W1T + (size_t)e*512*1088; K = 1088; J = 512;
    } else {
        int t2 = t - 816; int e = t2 >> 3; kt = t2 & 7; jt = 0;
        src = W2 + (size_t)e*512*64; dst = uws + U_W2T + (size_t)e*64*512; K = 512; J = 64;
    }
    int r = tid >> 2, c0 = (tid & 3) * 16;
    #pragma unroll
    for(int i = 0; i < 4; i++)
        *(f32x4*)&sT[r][c0 + i*4] = *(const f32x4*)&src[(size_t)(kt*64 + r)*J + jt*64 + c0 + i*4];
    __syncthreads();
    u16* d2 = dst + (size_t)(jt*64 + r)*K + kt*64;
    #pragma unroll
    for(int i = 0; i < 4; i++){
        u16x4 pk;
        pk.x = f2bf(sT[c0 + i*4 + 0][r]); pk.y = f2bf(sT[c0 + i*4 + 1][r]);
        pk.z = f2bf(sT[c0 + i*4 + 2][r]); pk.w = f2bf(sT[c0 + i*4 + 3][r]);
        *(u16x4*)&d2[c0 + i*4] = pk;
    }
}

// ---------------- k1: encoder + router, 1024 threads, one sample/block --------
#define PADX 72
__global__ __launch_bounds__(1024) void k1_enc(const float* __restrict__ obs,
        const u16* __restrict__ uws, const float* __restrict__ Wr,
        const float* __restrict__ br, const int* __restrict__ phase,
        const int* __restrict__ t_arr, float* __restrict__ ws){
    __shared__ u16  sX[256 * PADX];
    __shared__ float sBias[512];
    __shared__ float sG[512];
    __shared__ float sRed[8][6];
    int b = blockIdx.x, tid = threadIdx.x;
    {
        int row = tid >> 2, c0 = (tid & 3) * 16;
        const f32x4* src = (const f32x4*)&obs[((size_t)b*256 + row)*64 + c0];
        u16* dst = &sX[row*PADX + c0];
        #pragma unroll
        for(int i = 0; i < 4; i++){
            f32x4 v = src[i];
            u16x4 pk; pk.x = f2bf(v.x); pk.y = f2bf(v.y); pk.z = f2bf(v.z); pk.w = f2bf(v.w);
            *(u16x4*)(dst + i*4) = pk;
        }
    }
    if(tid < 512) sBias[tid] = ws[WS_BIAS + b*512 + tid];
    __syncthreads();
    int w = tid >> 6, l = tid & 63, lr = l & 15, lk = (l >> 4) * 8;
    const u16* wencT = uws + U_WENCT;
    s16x8 bf[2][2];
    float bias[2];
    #pragma unroll
    for(int n = 0; n < 2; n++){
        int col = w*32 + n*16 + lr;
        bf[n][0] = *(const s16x8*)&wencT[col*64 + lk];
        bf[n][1] = *(const s16x8*)&wencT[col*64 + 32 + lk];
        bias[n]  = sBias[col];
    }
    float cac[2] = {0.f, 0.f};
    for(int mt = 0; mt < 16; mt++){
        s16x8 a0 = *(const s16x8*)&sX[(mt*16 + lr)*PADX + lk];
        s16x8 a1 = *(const s16x8*)&sX[(mt*16 + lr)*PADX + 32 + lk];
        #pragma unroll
        for(int n = 0; n < 2; n++){
            f32x4 acc = {bias[n], bias[n], bias[n], bias[n]};
            mfma16(acc, a0, bf[n][0]);
            mfma16(acc, a1, bf[n][1]);
            cac[n] += gelu_f(acc.x) + gelu_f(acc.y) + gelu_f(acc.z) + gelu_f(acc.w);
        }
    }
    #pragma unroll
    for(int n = 0; n < 2; n++){
        cac[n] += __shfl_xor(cac[n], 16);
        cac[n] += __shfl_xor(cac[n], 32);
    }
    if(l < 16){
        #pragma unroll
        for(int n = 0; n < 2; n++)
            sG[w*32 + n*16 + l] = cac[n] * (1.0f/256.0f);
    }
    __syncthreads();
    if(tid < 512){
        float gv = sG[tid];
        u16* XC = (u16*)(ws + WS_XC);
        XC[b*1024 + tid] = f2bf(gv);
        int tv = t_arr[b];
        float fr = ws[WS_FREQS + (tid & 255)];
        float ang = (float)tv * fr;
        XC[b*1024 + 512 + tid] = f2bf((tid < 256) ? sinf(ang) : cosf(ang));
        float p6[6];
        #pragma unroll
        for(int e = 0; e < 6; e++) p6[e] = gv * Wr[tid*6 + e];
        #pragma unroll
        for(int off = 32; off > 0; off >>= 1)
            #pragma unroll
            for(int e = 0; e < 6; e++) p6[e] += __shfl_down(p6[e], off);
        if(l == 0)
            #pragma unroll
            for(int e = 0; e < 6; e++) sRed[w][e] = p6[e];
    }
    __syncthreads();
    if(tid == 0){
        float logit[6], mx = -1e30f;
        #pragma unroll
        for(int e = 0; e < 6; e++){
            float s = 0.f;
            #pragma unroll
            for(int q = 0; q < 8; q++) s += sRed[q][e];
            logit[e] = s + br[e];
            mx = fmaxf(mx, logit[e]);
        }
        float s = 0.f, p[6];
        #pragma unroll
        for(int e = 0; e < 6; e++){
            p[e] = __builtin_amdgcn_exp2f((logit[e] - mx) * 1.44269504f);
            s += p[e];
        }
        float inv = 1.0f / s;
        #pragma unroll
        for(int e = 0; e < 6; e++) ws[WS_PROBS + b*6 + e] = p[e] * inv;
        int ph = phase[b];
        int sel = ph + ((logit[ph + 3] > logit[ph]) ? 3 : 0);
        ((int*)ws)[WS_SELECTED + b] = sel;
    }
}

// ---------------- k3: hstat GEMM, K-split x2 (grid 224 = 14 chunks x 8 jt x 2 kh) --------
__global__ __launch_bounds__(256) void k3_hstat(const u16* __restrict__ uws,
        const float* __restrict__ b1, float* __restrict__ ws){
    __shared__ int sSrc[64], sDst[64];
    __shared__ int sCnt[8][6], sBase[8][6], sSec[6], sTot[6];
    __shared__ int sChunk[16][3];
    __shared__ int sNch;
    int bid = blockIdx.x, tid = threadIdx.x;
    int w = tid >> 6, l = tid & 63;
    int* wsi = (int*)ws;
    if(bid == 0 && tid == 0) wsi[WS_FLAG] = 0;   // reset k5 join counter
    int kh = bid & 1, jt = (bid >> 1) & 7, c = bid >> 4;
    int sv0 = wsi[WS_SELECTED + tid];
    int sv1 = wsi[WS_SELECTED + 256 + tid];
    unsigned long long mym0 = 0, mym1 = 0;
    #pragma unroll
    for(int e = 0; e < 6; e++){
        unsigned long long m0 = __ballot(sv0 == e);
        unsigned long long m1 = __ballot(sv1 == e);
        if(l == 0){ sCnt[w][e] = __popcll(m0); sCnt[4 + w][e] = __popcll(m1); }
        if(sv0 == e) mym0 = m0;
        if(sv1 == e) mym1 = m1;
    }
    if(tid < 64){ sSrc[tid] = 0; sDst[tid] = -1; }
    __syncthreads();
    if(tid == 0){
        int o = 0;
        for(int e = 0; e < 6; e++){
            sSec[e] = o; int t0 = 0;
            for(int g = 0; g < 8; g++){ sBase[g][e] = o; o += sCnt[g][e]; t0 += sCnt[g][e]; }
            sTot[e] = t0; o += 4;
        }
        int nch = 0;
        for(int e = 0; e < 6; e++){
            int len = sTot[e] + 4, st = sSec[e];
            for(int s = 0; s < len; s += 64){
                sChunk[nch][0] = e; sChunk[nch][1] = st + s;
                sChunk[nch][2] = (len - s < 64) ? (len - s) : 64; nch++;
            }
        }
        sNch = nch;
    }
    __syncthreads();
    if(c >= sNch) return;
    int e     = sChunk[c][0];
    int start = sChunk[c][1];
    int len   = sChunk[c][2];
    int hstatD  = kh ? WS_HSTATB  : WS_HSTAT;
    int hstat2D = kh ? WS_HSTAT2B : WS_HSTAT2;
    {
        int rank = __popcll(mym0 & ((1ull << l) - 1ull));
        int pos = sBase[w][sv0] + rank - start;
        if(pos >= 0 && pos < len){ sSrc[pos] = tid; sDst[pos] = hstatD + tid*512; }
    }
    {
        int rank = __popcll(mym1 & ((1ull << l) - 1ull));
        int pos = sBase[4 + w][sv1] + rank - start;
        if(pos >= 0 && pos < len){ sSrc[pos] = 256 + tid; sDst[pos] = hstatD + (256 + tid)*512; }
    }
    if(tid < 24){
        int ea = tid >> 2, ba = tid & 3;
        int pos = sSec[ea] + sTot[ea] + ba - start;
        if(pos >= 0 && pos < len){ sSrc[pos] = ba; sDst[pos] = hstat2D + (ea*4 + ba)*512; }
    }
    __syncthreads();
    int lr = l & 15, lk = (l >> 4) * 8;
    int col = jt*64 + w*16 + lr;
    const u16* XC = (const u16*)(ws + WS_XC);
    const u16* rowA[4];
    #pragma unroll
    for(int mt = 0; mt < 4; mt++)
        rowA[mt] = XC + (size_t)sSrc[mt*16 + lr]*1024 + kh*512 + lk;
    const u16* bp = uws + U_W1T + ((size_t)e*512 + col)*1088 + 64 + kh*512 + lk;
    f32x4 acc[4];
    {
        float bv = kh ? 0.f : b1[e*512 + col];
        f32x4 z = {bv, bv, bv, bv};
        #pragma unroll
        for(int mt = 0; mt < 4; mt++) acc[mt] = z;
    }
    #pragma unroll 4
    for(int ks = 0; ks < 16; ks++){
        s16x8 bb = *(const s16x8*)(bp + ks*32);
        s16x8 a0 = *(const s16x8*)(rowA[0] + ks*32);
        s16x8 a1 = *(const s16x8*)(rowA[1] + ks*32);
        s16x8 a2 = *(const s16x8*)(rowA[2] + ks*32);
        s16x8 a3 = *(const s16x8*)(rowA[3] + ks*32);
        mfma16(acc[0], a0, bb);
        mfma16(acc[1], a1, bb);
        mfma16(acc[2], a2, bb);
        mfma16(acc[3], a3, bb);
    }
    #pragma unroll
    for(int mt = 0; mt < 4; mt++){
        #pragma unroll
        for(int rg = 0; rg < 4; rg++){
            int r = mt*16 + (l >> 4)*4 + rg;
            int d = sDst[r];
            if(d >= 0) ws[d + col] = acc[mt][rg];
        }
    }
}

// ---------------- k4: FFN, 256 thr, 32-tf halves (grid 1072), 4 blocks/CU ----------------
#define PADN 72
#define PADH 520
__global__ __launch_bounds__(256) void k4_ffn(const float* __restrict__ fut,
        const float* __restrict__ eps, const int* __restrict__ t_arr,
        const u16* __restrict__ uws, const float* __restrict__ b2,
        float* __restrict__ ws){
    __shared__ u16 sN[32 * PADN];
    __shared__ u16 sH[32 * PADH];    // [tf][j]
    __shared__ float sHs[512];
    __shared__ float sRed[4];
    int tid = threadIdx.x, bid = blockIdx.x;
    int* wsi = (int*)ws;
    int b, e, store, half;
    if(bid < 48){ int idx = bid >> 1; half = bid & 1; e = idx >> 2; b = idx & 3; store = 1; }
    else { int r = bid - 48; b = r >> 1; half = r & 1; e = wsi[WS_SELECTED + b]; store = 0; }
    int tf0 = half * 32;
    if(store){
        int i2 = (e*4 + b)*512;
        sHs[tid]       = ws[WS_HSTAT2 + i2 + tid]       + ws[WS_HSTAT2B + i2 + tid];
        sHs[tid + 256] = ws[WS_HSTAT2 + i2 + tid + 256] + ws[WS_HSTAT2B + i2 + tid + 256];
    } else {
        sHs[tid]       = ws[WS_HSTAT + b*512 + tid]       + ws[WS_HSTATB + b*512 + tid];
        sHs[tid + 256] = ws[WS_HSTAT + b*512 + tid + 256] + ws[WS_HSTATB + b*512 + tid + 256];
    }
    int tv = t_arr[b];
    float ab = ws[WS_ALPHAS + tv];
    float sa = sqrtf(ab), sb = sqrtf(1.0f - ab);
    {   // stage 32 rows x 64 cols
        int r = tid >> 3, c0 = (tid & 7) * 8;
        const f32x4* pf = (const f32x4*)&fut[((size_t)b*64 + tf0 + r)*64 + c0];
        const f32x4* pe = (const f32x4*)&eps[((size_t)b*64 + tf0 + r)*64 + c0];
        f32x4 f0 = pf[0], f1 = pf[1], e0 = pe[0], e1 = pe[1];
        u16x4 p0, p1;
        p0.x = f2bf(sa*f0.x + sb*e0.x); p0.y = f2bf(sa*f0.y + sb*e0.y);
        p0.z = f2bf(sa*f0.z + sb*e0.z); p0.w = f2bf(sa*f0.w + sb*e0.w);
        p1.x = f2bf(sa*f1.x + sb*e1.x); p1.y = f2bf(sa*f1.y + sb*e1.y);
        p1.z = f2bf(sa*f1.z + sb*e1.z); p1.w = f2bf(sa*f1.w + sb*e1.w);
        *(u16x4*)&sN[r*PADN + c0]     = p0;
        *(u16x4*)&sN[r*PADN + c0 + 4] = p1;
    }
    __syncthreads();
    int w = tid >> 6, l = tid & 63, lr = l & 15, lk = (l >> 4) * 8;
    const u16* w1T = uws + U_W1T;
    const u16* w2T = uws + U_W2T;
    s16x8 nb[2][2];
    #pragma unroll
    for(int nt = 0; nt < 2; nt++){
        nb[nt][0] = *(const s16x8*)&sN[(nt*16 + lr)*PADN + lk];
        nb[nt][1] = *(const s16x8*)&sN[(nt*16 + lr)*PADN + 32 + lk];
    }
    #pragma unroll
    for(int mt = 0; mt < 8; mt++){
        int jrow = w*128 + mt*16 + lr;
        s16x8 aw0 = *(const s16x8*)&w1T[((size_t)e*512 + jrow)*1088 + lk];
        s16x8 aw1 = *(const s16x8*)&w1T[((size_t)e*512 + jrow)*1088 + 32 + lk];
        int j0 = w*128 + mt*16 + (l >> 4)*4;
        f32x4 hsv = *(const f32x4*)&sHs[j0];
        #pragma unroll
        for(int nt = 0; nt < 2; nt++){
            f32x4 acc = hsv;
            mfma16(acc, aw0, nb[nt][0]);
            mfma16(acc, aw1, nb[nt][1]);
            u16x4 pk;
            pk.x = f2bf(gelu_f(acc.x)); pk.y = f2bf(gelu_f(acc.y));
            pk.z = f2bf(gelu_f(acc.z)); pk.w = f2bf(gelu_f(acc.w));
            *(u16x4*)&sH[(nt*16 + lr)*PADH + j0] = pk;
        }
    }
    __syncthreads();
    int nt_o = w;
    f32x4 oacc[2];
    {
        float bz = b2[e*64 + nt_o*16 + lr];
        f32x4 z = {bz, bz, bz, bz}; oacc[0] = z; oacc[1] = z;
    }
    for(int ks = 0; ks < 16; ks++){
        s16x8 bb = *(const s16x8*)&w2T[((size_t)e*64 + nt_o*16 + lr)*512 + ks*32 + lk];
        #pragma unroll
        for(int i = 0; i < 2; i++){
            s16x8 a = *(const s16x8*)&sH[(i*16 + lr)*PADH + ks*32 + lk];
            mfma16(oacc[i], a, bb);
        }
    }
    if(store){
        #pragma unroll
        for(int i = 0; i < 2; i++)
            #pragma unroll
            for(int rg = 0; rg < 4; rg++){
                int row = tf0 + i*16 + (l >> 4)*4 + rg;
                int col = nt_o*16 + lr;
                ws[WS_OUTSUB + (e*4 + b)*4096 + row*64 + col] = oacc[i][rg];
            }
    } else {
        float ls = 0.f;
        #pragma unroll
        for(int i = 0; i < 2; i++)
            #pragma unroll
            for(int rg = 0; rg < 4; rg++){
                int row = tf0 + i*16 + (l >> 4)*4 + rg;
                int col = nt_o*16 + lr;
                float d = oacc[i][rg] - eps[((size_t)b*64 + row)*64 + col];
                ls += d*d;
            }
        #pragma unroll
        for(int off = 32; off > 0; off >>= 1) ls += __shfl_down(ls, off);
        if(l == 0) sRed[w] = ls;
        __syncthreads();
        if(tid == 0){
            float s = sRed[0] + sRed[1] + sRed[2] + sRed[3];
            ws[WS_LOSSB + half*512 + b] = s;   // raw; scaled+weighted in k5
        }
    }
}

// ---------------- k5: 52 partial blocks + atomic-join finalize ----------------
__global__ __launch_bounds__(256) void k5_final(float* __restrict__ ws, float* __restrict__ out){
    int bid = blockIdx.x, tid = threadIdx.x;
    int* wsi = (int*)ws;
    if(bid < 52){
        __shared__ float red[256];
        int part = bid >> 2, q = bid & 3;
        float s = 0.f;
        if(part < 7){
            const int pa[7] = {0,1,3,4,0,1,2};
            const int pb[7] = {1,2,4,5,3,4,5};
            const float* A  = &ws[WS_OUTSUB + pa[part]*16384];
            const float* Bp = &ws[WS_OUTSUB + pb[part]*16384];
            for(int i = q*1024 + tid; i < q*1024 + 1024; i += 256){
                f32x4 a = *(const f32x4*)&A[i*4];
                f32x4 c = *(const f32x4*)&Bp[i*4];
                f32x4 d = a - c;
                s += d.x*d.x + d.y*d.y + d.z*d.z + d.w*d.w;
            }
            s *= (1.0f/16384.0f);
        } else {
            int e = part - 7;
            const float* O = &ws[WS_OUTSUB + e*16384];
            for(int i = q*1008 + tid; i < q*1008 + 1008; i += 256){
                int sm = i / (63*16); int r = i % (63*16);
                int tf = r / 16; int f4 = (r % 16) * 4;
                f32x4 a = *(const f32x4*)&O[(sm*64 + tf + 1)*64 + f4];
                f32x4 c = *(const f32x4*)&O[(sm*64 + tf)*64 + f4];
                f32x4 d = a - c;
                s += d.x*d.x + d.y*d.y + d.z*d.z + d.w*d.w;
            }
            s *= (1.0f/16128.0f) * 0.5f;
        }
        red[tid] = s;
        __syncthreads();
        for(int st = 128; st > 0; st >>= 1){
            if(tid < st) red[tid] += red[tid + st];
            __syncthreads();
        }
        if(tid == 0){
            ws[WS_PARTS + bid] = red[0];
            __threadfence();
            atomicAdd(&wsi[WS_FLAG], 1);
        }
        return;
    }
    if(tid == 0){
        while(atomicAdd(&wsi[WS_FLAG], 0) < 52) __builtin_amdgcn_s_sleep(2);
    }
    __syncthreads();
    __threadfence();
    __shared__ float sW[4];
    __shared__ float sF[4][6], sP[4][6];
    int w = tid >> 6, l = tid & 63;
    int sel0 = wsi[WS_SELECTED + tid];
    int sel1 = wsi[WS_SELECTED + 256 + tid];
    float wg0 = (sel0 % 3 == 0) ? 1.f : 5.f;
    float wg1 = (sel1 % 3 == 0) ? 1.f : 5.f;
    float lv = (ws[WS_LOSSB + tid] + ws[WS_LOSSB + 512 + tid]) * (1.0f/4096.0f) * wg0
             + (ws[WS_LOSSB + 256 + tid] + ws[WS_LOSSB + 768 + tid]) * (1.0f/4096.0f) * wg1;
    float pv[6], cf[6];
    #pragma unroll
    for(int e = 0; e < 6; e++){
        pv[e] = ws[WS_PROBS + tid*6 + e] + ws[WS_PROBS + (256 + tid)*6 + e];
        cf[e] = ((sel0 == e) ? 1.f : 0.f) + ((sel1 == e) ? 1.f : 0.f);
    }
    #pragma unroll
    for(int off = 32; off > 0; off >>= 1){
        lv += __shfl_down(lv, off);
        #pragma unroll
        for(int e = 0; e < 6; e++){
            pv[e] += __shfl_down(pv[e], off);
            cf[e] += __shfl_down(cf[e], off);
        }
    }
    if(l == 0){
        sW[w] = lv;
        #pragma unroll
        for(int e = 0; e < 6; e++){ sF[w][e] = cf[e]; sP[w][e] = pv[e]; }
    }
    __syncthreads();
    if(tid == 0){
        float total = 0.f;
        for(int q = 0; q < 4; q++) total += sW[q];
        total *= (1.0f/512.0f);
        volatile float* vp = ws + WS_PARTS;
        float reg = 0.f;
        for(int p = 0; p < 52; p++) reg += vp[p];
        total += 0.01f * reg;
        float lb = 0.f;
        for(int e = 0; e < 6; e++){
            float f = 0.f, pp = 0.f;
            for(int q = 0; q < 4; q++){ f += sF[q][e]; pp += sP[q][e]; }
            lb += (f * (1.0f/512.f)) * (pp * (1.0f/512.f));
        }
        out[0] = total + 0.01f * 6.0f * lb;
    }
}

extern "C" void kernel_launch(void* const* d_in, const int* in_sizes, int n_in,
                              void* d_out, int out_size, void* d_ws, size_t ws_size,
                              hipStream_t stream){
    const float* obs  = (const float*)d_in[0];
    const float* fut  = (const float*)d_in[1];
    const float* stat = (const float*)d_in[2];
    const float* eps  = (const float*)d_in[3];
    const int*   phase= (const int*)d_in[4];
    const int*   t    = (const int*)d_in[5];
    const float* Wenc = (const float*)d_in[6];
    const float* benc = (const float*)d_in[7];
    const float* Wstat= (const float*)d_in[8];
    const float* Wr   = (const float*)d_in[9];
    const float* br   = (const float*)d_in[10];
    const float* W1   = (const float*)d_in[11];
    const float* b1   = (const float*)d_in[12];
    const float* W2   = (const float*)d_in[13];
    const float* b2   = (const float*)d_in[14];
    float* ws  = (float*)d_ws;
    u16*   uws = (u16*)((char*)d_ws + WS_U16BYTE);
    float* out = (float*)d_out;

    k0<<<937, 256, 0, stream>>>(Wenc, W1, W2, stat, Wstat, benc, uws, ws);
    k1_enc<<<512, 1024, 0, stream>>>(obs, uws, Wr, br, phase, t, ws);
    k3_hstat<<<224, 256, 0, stream>>>(uws, b1, ws);
    k4_ffn<<<1072, 256, 0, stream>>>(fut, eps, t, uws, b2, ws);
    k5_final<<<53, 256, 0, stream>>>(ws, out);
}